// Round 1
// baseline (97.708 us; speedup 1.0000x reference)
//
#include <hip/hip_runtime.h>
#include <hip/hip_bf16.h>

#define S 1024
#define U 128
#define D 64
#define EPSC 1e-7f

// Kernel 1: one block per speaker.
// Loads x[s] (128x64 f32 = 32KB) into LDS, computes normalized centroid,
// intra cos per utterance, argmin of clipped cos (first-index tie-break),
// writes centroid[s], sel[s] (hardest utterance), intra_d[s] = acos(min clipped cos).
__global__ __launch_bounds__(256) void k1_centroid_intra(
    const float* __restrict__ x, float* __restrict__ cent_g,
    float* __restrict__ sel_g, float* __restrict__ intra_g)
{
    __shared__ float xs[U * D];    // 32 KB
    __shared__ float part[4 * D];  // 1 KB
    __shared__ float cent[D];
    __shared__ float red[U];

    const int s = blockIdx.x;
    const int tid = threadIdx.x;

    // Stage x[s]: 8192 floats = 2048 float4; 256 threads x 8 iters, fully coalesced.
    const float4* __restrict__ xv = (const float4*)(x + (size_t)s * U * D);
    float4* xsv = (float4*)xs;
#pragma unroll
    for (int k = 0; k < 8; ++k) xsv[k * 256 + tid] = xv[k * 256 + tid];
    __syncthreads();

    // Centroid partial sums: thread (g,d), g=tid>>6 in 0..3, d=tid&63.
    // LDS addr u*64+d -> bank d%32 -> 2 lanes/bank (free).
    const int d = tid & 63, g = tid >> 6;
    float acc = 0.f;
    for (int u = g; u < U; u += 4) acc += xs[u * D + d];
    part[g * D + d] = acc;
    __syncthreads();

    if (tid < D) {
        float cm = (part[tid] + part[D + tid] + part[2 * D + tid] + part[3 * D + tid]) * (1.0f / U);
        float sq = cm * cm;
        // wave-64 butterfly sum
#pragma unroll
        for (int m = 1; m < 64; m <<= 1) sq += __shfl_xor(sq, m, 64);
        float nrm = fmaxf(sqrtf(sq), 1e-12f);
        float c = cm / nrm;
        cent[tid] = c;
        cent_g[s * D + tid] = c;
    }
    __syncthreads();

    // Intra cos: threads 0..127, one utterance each. Lane-staggered d order
    // so the column read xs[u*64+dd] spreads across banks (2-way, free).
    if (tid < U) {
        const int u = tid;
        const int off = u & 63;
        float a = 0.f;
#pragma unroll
        for (int k = 0; k < D; ++k) {
            int dd = (k + off) & 63;
            a = fmaf(xs[u * D + dd], cent[dd], a);
        }
        red[u] = fminf(fmaxf(a, -1.0f + EPSC), 1.0f - EPSC);
    }
    __syncthreads();

    // Argmin of clipped cos over 128 values, first-index tie-break (matches
    // reference argmax over arccos: arccos strictly decreasing, clip ties -> first idx).
    if (tid < 64) {
        float v0 = red[tid], v1 = red[tid + 64];
        float mv = fminf(v0, v1);
#pragma unroll
        for (int m = 1; m < 64; m <<= 1) mv = fminf(mv, __shfl_xor(mv, m, 64));
        int idx = (v0 == mv) ? tid : ((v1 == mv) ? (tid + 64) : (1 << 30));
#pragma unroll
        for (int m = 1; m < 64; m <<= 1) idx = min(idx, __shfl_xor(idx, m, 64));
        // all 64 lanes now hold the winning idx; copy hardest utterance out
        sel_g[s * D + tid] = xs[idx * D + tid];
        if (tid == 0) intra_g[s] = acosf(mv);
    }
}

// Kernel 2: 128 blocks x 8 speaker-rows. inter_d[s] over all t != s.
// Row s of the reference's pair pattern selects exactly centroids {0..S-1}\{s}
// (derivation: cent = c if c<s else c+1 for column c). min of arccos(clip) ==
// arccos(clip(max cos)).
__global__ __launch_bounds__(256) void k2_inter(
    const float* __restrict__ cent_g, const float* __restrict__ sel_g,
    const float* __restrict__ intra_g, float* __restrict__ terms)
{
    const int R = 8;
    __shared__ float sels[R * D];   // 2 KB
    __shared__ float cc[64 * D];    // 16 KB chunk of 64 centroids

    const int tid = threadIdx.x;
    const int s0 = blockIdx.x * R;

    if (tid < 128) ((float4*)sels)[tid] = ((const float4*)(sel_g + s0 * D))[tid];

    const int tl = tid & 63;   // local centroid column within chunk
    const int r0 = tid >> 6;   // wave id: handles rows r0 and r0+4
    float mx0 = -1e30f, mx1 = -1e30f;

    for (int c = 0; c < S / 64; ++c) {
        __syncthreads();
        const float4* __restrict__ cv = (const float4*)(cent_g + c * 64 * D);
        float4* ccv = (float4*)cc;
#pragma unroll
        for (int k = 0; k < 4; ++k) ccv[k * 256 + tid] = cv[k * 256 + tid];
        __syncthreads();

        const int t = c * 64 + tl;
        float a0 = 0.f, a1 = 0.f;
#pragma unroll
        for (int k = 0; k < D; ++k) {
            int dd = (k + tl) & 63;
            float cd = cc[tl * D + dd];
            a0 = fmaf(sels[r0 * D + dd], cd, a0);
            a1 = fmaf(sels[(r0 + 4) * D + dd], cd, a1);
        }
        if (t != s0 + r0) mx0 = fmaxf(mx0, a0);
        if (t != s0 + r0 + 4) mx1 = fmaxf(mx1, a1);
    }

#pragma unroll
    for (int m = 1; m < 64; m <<= 1) {
        mx0 = fmaxf(mx0, __shfl_xor(mx0, m, 64));
        mx1 = fmaxf(mx1, __shfl_xor(mx1, m, 64));
    }
    if (tl == 0) {
        int s = s0 + r0;
        float ic = fminf(fmaxf(mx0, -1.0f + EPSC), 1.0f - EPSC);
        terms[s] = fmaxf(0.5f + intra_g[s] - acosf(ic), 0.0f);
        s = s0 + r0 + 4;
        ic = fminf(fmaxf(mx1, -1.0f + EPSC), 1.0f - EPSC);
        terms[s] = fmaxf(0.5f + intra_g[s] - acosf(ic), 0.0f);
    }
}

// Kernel 3: deterministic single-block sum of 1024 terms -> scalar loss.
__global__ __launch_bounds__(256) void k3_sum(
    const float* __restrict__ terms, float* __restrict__ out)
{
    __shared__ float sred[4];
    const int tid = threadIdx.x;
    float a = 0.f;
    for (int i = tid; i < S; i += 256) a += terms[i];
#pragma unroll
    for (int m = 1; m < 64; m <<= 1) a += __shfl_xor(a, m, 64);
    if ((tid & 63) == 0) sred[tid >> 6] = a;
    __syncthreads();
    if (tid == 0) out[0] = sred[0] + sred[1] + sred[2] + sred[3];
}

extern "C" void kernel_launch(void* const* d_in, const int* in_sizes, int n_in,
                              void* d_out, int out_size, void* d_ws, size_t ws_size,
                              hipStream_t stream) {
    const float* x = (const float*)d_in[0];
    float* out = (float*)d_out;
    float* ws = (float*)d_ws;

    float* cent  = ws;                 // S*D
    float* sel   = ws + S * D;         // S*D
    float* intra = ws + 2 * S * D;     // S
    float* terms = ws + 2 * S * D + S; // S

    k1_centroid_intra<<<S, 256, 0, stream>>>(x, cent, sel, intra);
    k2_inter<<<S / 8, 256, 0, stream>>>(cent, sel, intra, terms);
    k3_sum<<<1, 256, 0, stream>>>(terms, out);
}

// Round 2
// 97.185 us; speedup vs baseline: 1.0054x; 1.0054x over previous
//
#include <hip/hip_runtime.h>
#include <hip/hip_bf16.h>

#define S 1024
#define U 128
#define D 64
#define EPSC 1e-7f

// Kernel 1: one block per speaker.
// Loads x[s] (128x64 f32 = 32KB) into LDS, computes normalized centroid,
// intra cos per utterance, argmin of clipped cos (first-index tie-break),
// writes centroid[s], sel[s] (hardest utterance), intra_d[s] = acos(min clipped cos).
// Also: block 0 initializes the cross-kernel atomic counter (ws is re-poisoned
// to 0xAA before every launch; k1 completes before k2 starts, stream-ordered).
__global__ __launch_bounds__(256) void k1_centroid_intra(
    const float* __restrict__ x, float* __restrict__ cent_g,
    float* __restrict__ sel_g, float* __restrict__ intra_g,
    int* __restrict__ counter)
{
    __shared__ float xs[U * D];    // 32 KB
    __shared__ float part[4 * D];  // 1 KB
    __shared__ float cent[D];
    __shared__ float red[U];

    const int s = blockIdx.x;
    const int tid = threadIdx.x;

    if (s == 0 && tid == 0) counter[0] = 0;

    // Stage x[s]: 8192 floats = 2048 float4; 256 threads x 8 iters, fully coalesced.
    const float4* __restrict__ xv = (const float4*)(x + (size_t)s * U * D);
    float4* xsv = (float4*)xs;
#pragma unroll
    for (int k = 0; k < 8; ++k) xsv[k * 256 + tid] = xv[k * 256 + tid];
    __syncthreads();

    // Centroid partial sums: thread (g,d), g=tid>>6 in 0..3, d=tid&63.
    // LDS addr u*64+d -> bank d%32 -> 2 lanes/bank (free).
    const int d = tid & 63, g = tid >> 6;
    float acc = 0.f;
    for (int u = g; u < U; u += 4) acc += xs[u * D + d];
    part[g * D + d] = acc;
    __syncthreads();

    if (tid < D) {
        float cm = (part[tid] + part[D + tid] + part[2 * D + tid] + part[3 * D + tid]) * (1.0f / U);
        float sq = cm * cm;
#pragma unroll
        for (int m = 1; m < 64; m <<= 1) sq += __shfl_xor(sq, m, 64);
        float nrm = fmaxf(sqrtf(sq), 1e-12f);
        float c = cm / nrm;
        cent[tid] = c;
        cent_g[s * D + tid] = c;
    }
    __syncthreads();

    // Intra cos: threads 0..127, one utterance each. Lane-staggered d order
    // so the column read xs[u*64+dd] spreads across banks (2-way, free).
    if (tid < U) {
        const int u = tid;
        const int off = u & 63;
        float a = 0.f;
#pragma unroll
        for (int k = 0; k < D; ++k) {
            int dd = (k + off) & 63;
            a = fmaf(xs[u * D + dd], cent[dd], a);
        }
        red[u] = fminf(fmaxf(a, -1.0f + EPSC), 1.0f - EPSC);
    }
    __syncthreads();

    // Argmin of clipped cos over 128 values, first-index tie-break (matches
    // reference argmax over arccos: arccos strictly decreasing, clip ties -> first idx).
    if (tid < 64) {
        float v0 = red[tid], v1 = red[tid + 64];
        float mv = fminf(v0, v1);
#pragma unroll
        for (int m = 1; m < 64; m <<= 1) mv = fminf(mv, __shfl_xor(mv, m, 64));
        int idx = (v0 == mv) ? tid : ((v1 == mv) ? (tid + 64) : (1 << 30));
#pragma unroll
        for (int m = 1; m < 64; m <<= 1) idx = min(idx, __shfl_xor(idx, m, 64));
        sel_g[s * D + tid] = xs[idx * D + tid];
        if (tid == 0) intra_g[s] = acosf(mv);
    }
}

// Kernel 2 (fused inter + final sum): 256 blocks x 4 speaker rows, barrier-free
// hot loop. Thread owns centroid t = i*256+tid, reads its 64-float row straight
// into registers (16 independent float4 loads -> latency hidden, L2-resident,
// each lane consumes whole 64B lines so no over-fetch). sel rows live in LDS,
// read as wave-broadcasts (same-address = conflict-free).
// Last-block pattern (partials + device fence + atomic counter) folds the final
// deterministic sum in, eliminating the k3 launch.
__global__ __launch_bounds__(256) void k2_inter_sum(
    const float* __restrict__ cent_g, const float* __restrict__ sel_g,
    const float* __restrict__ intra_g, float* __restrict__ partials,
    int* __restrict__ counter, float* __restrict__ out)
{
    __shared__ float4 sels4[4 * 16];  // 4 rows x 64 floats = 1 KB
    __shared__ float wred[4][4];      // [wave][row]
    __shared__ float sred[4];
    __shared__ int lastflag;

    const int tid = threadIdx.x;
    const int s0 = blockIdx.x * 4;

    if (tid < 64) sels4[tid] = ((const float4*)(sel_g + (size_t)s0 * D))[tid];
    __syncthreads();

    float mx0 = -1e30f, mx1 = -1e30f, mx2 = -1e30f, mx3 = -1e30f;

#pragma unroll
    for (int i = 0; i < 4; ++i) {
        const int t = i * 256 + tid;
        const float4* __restrict__ cp = (const float4*)(cent_g + (size_t)t * D);
        float a0 = 0.f, a1 = 0.f, a2 = 0.f, a3 = 0.f;
#pragma unroll
        for (int k = 0; k < 16; ++k) {
            const float4 c = cp[k];
            const float4 r0 = sels4[k];
            const float4 r1 = sels4[16 + k];
            const float4 r2 = sels4[32 + k];
            const float4 r3 = sels4[48 + k];
            a0 = fmaf(c.x, r0.x, fmaf(c.y, r0.y, fmaf(c.z, r0.z, fmaf(c.w, r0.w, a0))));
            a1 = fmaf(c.x, r1.x, fmaf(c.y, r1.y, fmaf(c.z, r1.z, fmaf(c.w, r1.w, a1))));
            a2 = fmaf(c.x, r2.x, fmaf(c.y, r2.y, fmaf(c.z, r2.z, fmaf(c.w, r2.w, a2))));
            a3 = fmaf(c.x, r3.x, fmaf(c.y, r3.y, fmaf(c.z, r3.z, fmaf(c.w, r3.w, a3))));
        }
        if (t != s0)     mx0 = fmaxf(mx0, a0);
        if (t != s0 + 1) mx1 = fmaxf(mx1, a1);
        if (t != s0 + 2) mx2 = fmaxf(mx2, a2);
        if (t != s0 + 3) mx3 = fmaxf(mx3, a3);
    }

#pragma unroll
    for (int m = 1; m < 64; m <<= 1) {
        mx0 = fmaxf(mx0, __shfl_xor(mx0, m, 64));
        mx1 = fmaxf(mx1, __shfl_xor(mx1, m, 64));
        mx2 = fmaxf(mx2, __shfl_xor(mx2, m, 64));
        mx3 = fmaxf(mx3, __shfl_xor(mx3, m, 64));
    }
    const int w = tid >> 6;
    if ((tid & 63) == 0) {
        wred[w][0] = mx0; wred[w][1] = mx1; wred[w][2] = mx2; wred[w][3] = mx3;
    }
    __syncthreads();

    if (tid < 4) {
        float m = fmaxf(fmaxf(wred[0][tid], wred[1][tid]),
                        fmaxf(wred[2][tid], wred[3][tid]));
        float ic = fminf(fmaxf(m, -1.0f + EPSC), 1.0f - EPSC);
        wred[0][tid] = fmaxf(0.5f + intra_g[s0 + tid] - acosf(ic), 0.0f);
    }
    __syncthreads();

    if (tid == 0) {
        partials[blockIdx.x] = wred[0][0] + wred[0][1] + wred[0][2] + wred[0][3];
        __threadfence();  // release partials (device scope, cross-XCD)
        int old = atomicAdd(counter, 1);
        lastflag = (old == (int)gridDim.x - 1) ? 1 : 0;
    }
    __syncthreads();

    if (lastflag) {
        __threadfence();  // acquire: all 256 partials are now globally visible
        float a = partials[tid];  // blockDim == gridDim == 256
#pragma unroll
        for (int m = 1; m < 64; m <<= 1) a += __shfl_xor(a, m, 64);
        if ((tid & 63) == 0) sred[tid >> 6] = a;
        __syncthreads();
        if (tid == 0) out[0] = sred[0] + sred[1] + sred[2] + sred[3];
    }
}

extern "C" void kernel_launch(void* const* d_in, const int* in_sizes, int n_in,
                              void* d_out, int out_size, void* d_ws, size_t ws_size,
                              hipStream_t stream) {
    const float* x = (const float*)d_in[0];
    float* out = (float*)d_out;
    float* ws = (float*)d_ws;

    float* cent     = ws;                       // S*D
    float* sel      = ws + S * D;               // S*D
    float* intra    = ws + 2 * S * D;           // S
    float* partials = ws + 2 * S * D + S;       // 256
    int*   counter  = (int*)(ws + 2 * S * D + S + 256);

    k1_centroid_intra<<<S, 256, 0, stream>>>(x, cent, sel, intra, counter);
    k2_inter_sum<<<S / 4, 256, 0, stream>>>(cent, sel, intra, partials, counter, out);
}